// Round 12
// baseline (28.362 us; speedup 1.0000x reference)
//
#include <hip/hip_runtime.h>

// PSRoIPool: features (B=2, C=1029, H=100, W=100) f32, rois (R=512, 5) f32.
// Output: (R, D=21, P=7, P=7) f32;  out[r*1029 + ch], ch=(d*7+ph)*7+pw.
//
// Correctness-critical (round 7): window bounds must match XLA-CPU fast-math:
// bin = roi * float(1/7) (reciprocal multiply, NOT true divide), then
// fmaf(p, bin, s). Changing either re-breaks the knife-edge ROI (absmax 0.6).
//
// Perf (round 12): r11 structure (block/channel, float4 row loads; windows
// provably <=4x4) with ONE ROI PER THREAD: grid = NCH x R/256 = 2058 blocks
// -> ~32 waves/CU (2x r11), removing the serial 2nd ROI iteration per thread.
// r11 was latency-bound at ~1.5 TB/s effective with ~16 waves/CU; this buys
// 2x the in-flight memory chains at identical traffic shape.

#define POOLED 7
#define GROUP 7
#define OUT_DIM 21
#define FH 100
#define FW 100
#define NCH (OUT_DIM * GROUP * GROUP)  // 1029
#define PLANE (FH * FW)                // 10000
#define PER_ROI NCH

typedef float f4 __attribute__((ext_vector_type(4)));
typedef f4 __attribute__((aligned(4))) f4u;   // dword-aligned vector load

__device__ __forceinline__ float fbar(float x) { asm volatile("" : "+v"(x)); return x; }

__global__ __launch_bounds__(256) void psroi_f4_kernel(
    const float* __restrict__ feat,
    const float* __restrict__ rois,
    float* __restrict__ out,
    int R)
{
    const int ch  = blockIdx.x;                      // 0..1028
    const int r   = blockIdx.y * 256 + threadIdx.x;  // one ROI per thread
    if (r >= R) return;

    const int pw = ch % GROUP;
    const int ph = (ch / GROUP) % GROUP;

    const float rcp7  = 1.0f / 7.0f;
    const float scale = 0.0625f;
    const float phf = (float)ph;
    const float pwf = (float)pw;

    const float* roi = rois + (size_t)r * 5;
    int b = (int)roi[0];

    // exact f32 (multiples of 2^-4 < 128):
    float sw = rintf(roi[1]) * scale;
    float sh = rintf(roi[2]) * scale;
    float ew = (rintf(roi[3]) + 1.0f) * scale;
    float eh = (rintf(roi[4]) + 1.0f) * scale;
    float roi_w = fmaxf(ew - sw, 0.1f);
    float roi_h = fmaxf(eh - sh, 0.1f);

    // XLA-CPU fast-math semantics: reciprocal multiply + fused mul-add
    float bin_w = fbar(roi_w * rcp7);
    float bin_h = fbar(roi_h * rcp7);
    float th0 = __builtin_fmaf(phf,        bin_h, sh);
    float th1 = __builtin_fmaf(phf + 1.0f, bin_h, sh);
    float tw0 = __builtin_fmaf(pwf,        bin_w, sw);
    float tw1 = __builtin_fmaf(pwf + 1.0f, bin_w, sw);

    int hs = (int)fminf(fmaxf(floorf(th0), 0.0f), (float)FH);
    int he = (int)fminf(fmaxf(ceilf(th1),  0.0f), (float)FH);
    int ws = (int)fminf(fmaxf(floorf(tw0), 0.0f), (float)FW);
    int we = (int)fminf(fmaxf(ceilf(tw1),  0.0f), (float)FW);

    int H  = he - hs;                 // 0..4
    int Wd = we - ws;                 // 0..4

    int wl = min(ws, FW - 4);         // clamped row start, always in-bounds
    int j0 = ws - wl;                 // first valid element index in f4
    int j1 = j0 + Wd;                 // one past last valid
    const float* p = feat + ((size_t)b * NCH + ch) * PLANE + hs * FW + wl;

    float s = 0.0f;
    #pragma unroll
    for (int hh = 0; hh < 4; ++hh) {
        if (hh < H) {
            f4 v = *(const f4u*)(p + hh * FW);   // one dwordx4 per row
            #pragma unroll
            for (int k = 0; k < 4; ++k) {
                s += (k >= j0 && k < j1) ? v[k] : 0.0f;
            }
        }
    }
    int area = H * Wd;
    out[(size_t)r * PER_ROI + ch] = (area > 0) ? s / (float)area : 0.0f;
}

extern "C" void kernel_launch(void* const* d_in, const int* in_sizes, int n_in,
                              void* d_out, int out_size, void* d_ws, size_t ws_size,
                              hipStream_t stream) {
    const float* feat = (const float*)d_in[0];
    const float* rois = (const float*)d_in[1];
    float* out = (float*)d_out;
    int R = in_sizes[1] / 5;  // 512
    dim3 grid(NCH, (R + 255) / 256);
    psroi_f4_kernel<<<grid, 256, 0, stream>>>(feat, rois, out, R);
}

// Round 13
// 26.013 us; speedup vs baseline: 1.0903x; 1.0903x over previous
//
#include <hip/hip_runtime.h>

// PSRoIPool: features (B=2, C=1029, H=100, W=100) f32, rois (R=512, 5) f32.
// Output: (R, D=21, P=7, P=7) f32;  out[r*1029 + ch], ch=(d*7+ph)*7+pw.
//
// Correctness-critical (round 7): window bounds must match XLA-CPU fast-math:
// bin = roi * float(1/7) (reciprocal multiply, NOT true divide), then
// fmaf(p, bin, s). Changing either re-breaks the knife-edge ROI (absmax 0.6).
//
// Perf (round 13): MLP-max. r12 post-mortem: 2x waves -> no change; r11/r12
// are per-thread-serial-chain limited (roi load -> bounds -> gathers -> wait),
// ~4 lines in flight/lane, ~2 TB/s scattered-line delivery. This round each
// thread handles 4 ROIs EXPLICITLY IN PARALLEL: 4 roi loads + 16 independent
// dwordx4 gathers all issued before any use. Rows are loaded unconditionally
// with clamp hr=hs+min(hh,H-1): clamped rows re-touch lines valid rows fetch
// anyway (no FETCH inflation, unlike r10's 4x4-always scheme). Windows are
// provably <=4x4 and non-empty (bin<=2.83, bin>0 => ceil>floor).

#define POOLED 7
#define GROUP 7
#define OUT_DIM 21
#define FH 100
#define FW 100
#define NCH (OUT_DIM * GROUP * GROUP)  // 1029
#define PLANE (FH * FW)                // 10000
#define PER_ROI NCH
#define RPT 4                          // ROIs per thread
#define BLK 128                        // threads per block; BLK*RPT == R

typedef float f4 __attribute__((ext_vector_type(4)));
typedef f4 __attribute__((aligned(4))) f4u;   // dword-aligned vector load

__device__ __forceinline__ float fbar(float x) { asm volatile("" : "+v"(x)); return x; }

__global__ __launch_bounds__(BLK) void psroi_mlp_kernel(
    const float* __restrict__ feat,
    const float* __restrict__ rois,
    float* __restrict__ out,
    int R)
{
    const int ch  = blockIdx.x;          // 0..1028
    const int tid = threadIdx.x;

    const int pw = ch % GROUP;
    const int ph = (ch / GROUP) % GROUP;

    const float rcp7  = 1.0f / 7.0f;
    const float scale = 0.0625f;
    const float phf = (float)ph;
    const float pwf = (float)pw;

    int   rr[RPT];
    int   H[RPT], Wd[RPT], j0[RPT], j1[RPT];
    const float* base[RPT];
    f4    v[RPT][4];

    // ---- phase 1a: bounds for all RPT ROIs (independent roi loads) ----
    #pragma unroll
    for (int i = 0; i < RPT; ++i) {
        int r = tid + i * BLK;
        rr[i] = r;
        const float* roi = rois + (size_t)r * 5;
        int b = (int)roi[0];

        float sw = rintf(roi[1]) * scale;
        float sh = rintf(roi[2]) * scale;
        float ew = (rintf(roi[3]) + 1.0f) * scale;
        float eh = (rintf(roi[4]) + 1.0f) * scale;
        float roi_w = fmaxf(ew - sw, 0.1f);
        float roi_h = fmaxf(eh - sh, 0.1f);

        // XLA-CPU fast-math semantics: reciprocal multiply + fused mul-add
        float bin_w = fbar(roi_w * rcp7);
        float bin_h = fbar(roi_h * rcp7);
        float th0 = __builtin_fmaf(phf,        bin_h, sh);
        float th1 = __builtin_fmaf(phf + 1.0f, bin_h, sh);
        float tw0 = __builtin_fmaf(pwf,        bin_w, sw);
        float tw1 = __builtin_fmaf(pwf + 1.0f, bin_w, sw);

        int hs = (int)fminf(fmaxf(floorf(th0), 0.0f), (float)FH);
        int he = (int)fminf(fmaxf(ceilf(th1),  0.0f), (float)FH);
        int ws = (int)fminf(fmaxf(floorf(tw0), 0.0f), (float)FW);
        int we = (int)fminf(fmaxf(ceilf(tw1),  0.0f), (float)FW);

        H[i]  = he - hs;              // 1..4
        Wd[i] = we - ws;              // 1..4
        int wl = min(ws, FW - 4);     // clamped row start, always in-bounds
        j0[i] = ws - wl;
        j1[i] = j0[i] + Wd[i];
        base[i] = feat + ((size_t)b * NCH + ch) * PLANE + hs * FW + wl;
    }

    // ---- phase 1b: issue all 16 gathers, fully independent ----
    #pragma unroll
    for (int i = 0; i < RPT; ++i) {
        int hm = H[i] - 1;
        #pragma unroll
        for (int hh = 0; hh < 4; ++hh) {
            int hr = (hh < hm) ? hh : hm;          // clamp: stays on fetched rows
            v[i][hh] = *(const f4u*)(base[i] + hr * FW);
        }
    }

    // ---- phase 2: masked sums, divides, stores ----
    #pragma unroll
    for (int i = 0; i < RPT; ++i) {
        float s = 0.0f;
        #pragma unroll
        for (int hh = 0; hh < 4; ++hh) {
            if (hh < H[i]) {
                #pragma unroll
                for (int k = 0; k < 4; ++k) {
                    s += (k >= j0[i] && k < j1[i]) ? v[i][hh][k] : 0.0f;
                }
            }
        }
        int area = H[i] * Wd[i];
        out[(size_t)rr[i] * PER_ROI + ch] = (area > 0) ? s / (float)area : 0.0f;
    }
}

extern "C" void kernel_launch(void* const* d_in, const int* in_sizes, int n_in,
                              void* d_out, int out_size, void* d_ws, size_t ws_size,
                              hipStream_t stream) {
    const float* feat = (const float*)d_in[0];
    const float* rois = (const float*)d_in[1];
    float* out = (float*)d_out;
    int R = in_sizes[1] / 5;  // 512 == BLK * RPT
    psroi_mlp_kernel<<<NCH, BLK, 0, stream>>>(feat, rois, out, R);
}

// Round 14
// 25.107 us; speedup vs baseline: 1.1296x; 1.0361x over previous
//
#include <hip/hip_runtime.h>

// PSRoIPool: features (B=2, C=1029, H=100, W=100) f32, rois (R=512, 5) f32.
// Output: (R, D=21, P=7, P=7) f32;  out[r*1029 + ch], ch=(d*7+ph)*7+pw.
//
// Correctness-critical (round 7): window bounds must match XLA-CPU fast-math:
// bin = roi * float(1/7) (reciprocal multiply, NOT true divide), then
// fmaf(p, bin, s). Changing either re-breaks the knife-edge ROI (absmax 0.6).
//
// Perf (round 14): r12/r13 nulls proved the gather path is pinned at the
// scattered-line roofline (~1.5 TB/s, 40MB/26us). Switch to chunked COALESCED
// streaming: block = (channel, 28-row chunk), grid 1029x4, LDS 22.4KB ->
// 7 blocks/CU = 28 waves/CU (r8 failed at 2 blocks/CU, 835 GB/s), reg-staged
// 6-deep f4 loads (all issued before any ds_write). A ROI is computed by the
// unique chunk containing hs (windows <=4 rows <= 3-row overlap). Traffic:
// 109/100 rows = ~90MB streamed at ~5 TB/s beats 40MB gathered at 1.5.

#define POOLED 7
#define GROUP 7
#define OUT_DIM 21
#define FH 100
#define FW 100
#define NCH (OUT_DIM * GROUP * GROUP)  // 1029
#define PLANE (FH * FW)                // 10000
#define CH_ROWS 28                     // staged rows per chunk
#define CH_STRIDE 25                   // chunk ownership stride
#define NF4MAX 700                     // 28*100/4 f4s per plane

typedef float f4 __attribute__((ext_vector_type(4)));
typedef f4 __attribute__((aligned(16))) f4a;

__device__ __forceinline__ float fbar(float x) { asm volatile("" : "+v"(x)); return x; }

__global__ __launch_bounds__(256) void psroi_stream_kernel(
    const float* __restrict__ feat,
    const float* __restrict__ rois,
    float* __restrict__ out,
    int R)
{
    __shared__ float lds[2 * CH_ROWS * FW];   // [b][row][col], 22.4 KB
    const int ch   = blockIdx.x;              // 0..1028
    const int c    = blockIdx.y;              // chunk 0..3
    const int row0 = c * CH_STRIDE;
    const int nrows = (FH - row0 < CH_ROWS) ? (FH - row0) : CH_ROWS;  // 28,28,28,25
    const int nf4  = nrows * (FW / 4);        // f4s per plane (700 or 625)
    const int tid  = threadIdx.x;

    const int pw = ch % GROUP;
    const int ph = (ch / GROUP) % GROUP;
    const float rcp7  = 1.0f / 7.0f;
    const float scale = 0.0625f;
    const float phf = (float)ph;
    const float pwf = (float)pw;

    // ---- bounds for this thread's 2 ROIs (registers; bit-exact r7 math) ----
    int rH[2], rW[2], rhs[2], rws[2], rb[2], rr[2];
    #pragma unroll
    for (int i = 0; i < 2; ++i) {
        int r = tid + i * 256;
        rr[i] = r;
        const float* roi = rois + (size_t)r * 5;
        rb[i] = (int)roi[0];

        float sw = rintf(roi[1]) * scale;
        float sh = rintf(roi[2]) * scale;
        float ew = (rintf(roi[3]) + 1.0f) * scale;
        float eh = (rintf(roi[4]) + 1.0f) * scale;
        float roi_w = fmaxf(ew - sw, 0.1f);
        float roi_h = fmaxf(eh - sh, 0.1f);

        float bin_w = fbar(roi_w * rcp7);
        float bin_h = fbar(roi_h * rcp7);
        float th0 = __builtin_fmaf(phf,        bin_h, sh);
        float th1 = __builtin_fmaf(phf + 1.0f, bin_h, sh);
        float tw0 = __builtin_fmaf(pwf,        bin_w, sw);
        float tw1 = __builtin_fmaf(pwf + 1.0f, bin_w, sw);

        int hs = (int)fminf(fmaxf(floorf(th0), 0.0f), (float)FH);
        int he = (int)fminf(fmaxf(ceilf(th1),  0.0f), (float)FH);
        int ws = (int)fminf(fmaxf(floorf(tw0), 0.0f), (float)FW);
        int we = (int)fminf(fmaxf(ceilf(tw1),  0.0f), (float)FW);
        rhs[i] = hs; rH[i] = he - hs; rws[i] = ws; rW[i] = we - ws;
    }

    // ---- reg-staged coalesced load: 3 f4 per plane per thread, 6 in flight ----
    const f4a* s0 = (const f4a*)(feat + (size_t)ch * PLANE + row0 * FW);
    const f4a* s1 = (const f4a*)(feat + ((size_t)NCH + ch) * PLANE + row0 * FW);
    f4 tA[3], tB[3];
    #pragma unroll
    for (int k = 0; k < 3; ++k) {
        int i = tid + k * 256;
        if (i < nf4) tA[k] = s0[i];
    }
    #pragma unroll
    for (int k = 0; k < 3; ++k) {
        int i = tid + k * 256;
        if (i < nf4) tB[k] = s1[i];
    }
    f4* ldsv = (f4*)lds;
    #pragma unroll
    for (int k = 0; k < 3; ++k) {
        int i = tid + k * 256;
        if (i < nf4) ldsv[i] = tA[k];
    }
    #pragma unroll
    for (int k = 0; k < 3; ++k) {
        int i = tid + k * 256;
        if (i < nf4) ldsv[NF4MAX + i] = tB[k];
    }
    __syncthreads();

    // ---- compute: each ROI handled by the unique chunk containing hs ----
    #pragma unroll
    for (int i = 0; i < 2; ++i) {
        int hs = rhs[i];
        if (hs >= row0 && hs < row0 + CH_STRIDE) {
            int H = rH[i], Wd = rW[i];
            const float* base = lds + rb[i] * (CH_ROWS * FW) + (hs - row0) * FW;
            float s = 0.0f;
            #pragma unroll
            for (int hh = 0; hh < 4; ++hh) {
                int rrow = (hh < H) ? hh : (H - 1);      // clamped: stays staged
                const float* rowp = base + rrow * FW;
                #pragma unroll
                for (int k = 0; k < 4; ++k) {
                    int w = rws[i] + k;
                    float v = rowp[(w < FW - 1) ? w : (FW - 1)];
                    s += (hh < H && k < Wd) ? v : 0.0f;
                }
            }
            int area = H * Wd;
            out[(size_t)rr[i] * NCH + ch] = (area > 0) ? s / (float)area : 0.0f;
        }
    }
}

extern "C" void kernel_launch(void* const* d_in, const int* in_sizes, int n_in,
                              void* d_out, int out_size, void* d_ws, size_t ws_size,
                              hipStream_t stream) {
    const float* feat = (const float*)d_in[0];
    const float* rois = (const float*)d_in[1];
    float* out = (float*)d_out;
    int R = in_sizes[1] / 5;  // 512 (= 2 * 256 threads)
    dim3 grid(NCH, (FH + CH_STRIDE - 1) / CH_STRIDE);  // 1029 x 4
    psroi_stream_kernel<<<grid, 256, 0, stream>>>(feat, rois, out, R);
}

// Round 15
// 22.937 us; speedup vs baseline: 1.2365x; 1.0946x over previous
//
#include <hip/hip_runtime.h>

// PSRoIPool: features (B=2, C=1029, H=100, W=100) f32, rois (R=512, 5) f32.
// Output: (R, D=21, P=7, P=7) f32;  out[r*1029 + ch], ch=(d*7+ph)*7+pw.
//
// Correctness-critical (round 7): window bounds must match XLA-CPU fast-math:
// bin = roi * float(1/7) (reciprocal multiply, NOT true divide), then
// fmaf(p, bin, s). Changing either re-breaks the knife-edge ROI (absmax 0.6).
//
// Perf (round 15): full-plane-pair staging at FULL occupancy. r14 streamed at
// only ~3.7 TB/s; r8's full-plane version failed at 8 waves/CU (2 blocks x 4
// waves). Here: 1024-thread blocks, 80 KB LDS -> 2 blocks/CU = 32 waves/CU,
// 1029 blocks = 2 clean rounds. Minimal stream traffic (82 MB, no chunk
// overlap, bounds computed ONCE per ROI). 6 reg-staged dwordx4 loads issued
// first; ROI bounds math executes in their latency shadow; one sync; t<512
// sums its ROI's <=4x4 window from LDS.

#define POOLED 7
#define GROUP 7
#define OUT_DIM 21
#define FH 100
#define FW 100
#define NCH (OUT_DIM * GROUP * GROUP)  // 1029
#define PLANE (FH * FW)                // 10000 floats
#define NF4 (PLANE / 4)                // 2500 f4 per plane

typedef float f4 __attribute__((ext_vector_type(4)));
typedef f4 __attribute__((aligned(16))) f4a;

__device__ __forceinline__ float fbar(float x) { asm volatile("" : "+v"(x)); return x; }

__global__ __launch_bounds__(1024) void psroi_full_kernel(
    const float* __restrict__ feat,
    const float* __restrict__ rois,
    float* __restrict__ out,
    int R)
{
    __shared__ float lds[2 * PLANE];          // 80 KB: planes for b=0, b=1
    const int ch  = blockIdx.x;               // 0..1028
    const int tid = threadIdx.x;              // 0..1023

    // ---- issue all staging loads first (6 independent dwordx4) ----
    const f4a* s0 = (const f4a*)(feat + (size_t)ch * PLANE);          // b=0
    const f4a* s1 = (const f4a*)(feat + ((size_t)NCH + ch) * PLANE);  // b=1
    const bool tail = tid < (NF4 - 2048);     // 452 threads carry the remainder
    f4 a0 = s0[tid];
    f4 a1 = s0[tid + 1024];
    f4 a2 = tail ? s0[tid + 2048] : f4{0, 0, 0, 0};
    f4 b0 = s1[tid];
    f4 b1 = s1[tid + 1024];
    f4 b2 = tail ? s1[tid + 2048] : f4{0, 0, 0, 0};

    // ---- ROI bounds in the load-latency shadow (thread t<512 owns ROI t) ----
    int H = 0, Wd = 0, hs = 0, ws = 0, b = 0;
    if (tid < R) {
        const float* roi = rois + (size_t)tid * 5;
        b = (int)roi[0];
        const float rcp7  = 1.0f / 7.0f;
        const float scale = 0.0625f;
        const int pw = ch % GROUP;
        const int ph = (ch / GROUP) % GROUP;
        const float phf = (float)ph;
        const float pwf = (float)pw;

        float sw = rintf(roi[1]) * scale;     // exact f32: k/16, k<25600
        float sh = rintf(roi[2]) * scale;
        float ew = (rintf(roi[3]) + 1.0f) * scale;
        float eh = (rintf(roi[4]) + 1.0f) * scale;
        float roi_w = fmaxf(ew - sw, 0.1f);
        float roi_h = fmaxf(eh - sh, 0.1f);

        // XLA-CPU fast-math semantics: reciprocal multiply + fused mul-add
        float bin_w = fbar(roi_w * rcp7);
        float bin_h = fbar(roi_h * rcp7);
        float th0 = __builtin_fmaf(phf,        bin_h, sh);
        float th1 = __builtin_fmaf(phf + 1.0f, bin_h, sh);
        float tw0 = __builtin_fmaf(pwf,        bin_w, sw);
        float tw1 = __builtin_fmaf(pwf + 1.0f, bin_w, sw);

        int hs_ = (int)fminf(fmaxf(floorf(th0), 0.0f), (float)FH);
        int he_ = (int)fminf(fmaxf(ceilf(th1),  0.0f), (float)FH);
        int ws_ = (int)fminf(fmaxf(floorf(tw0), 0.0f), (float)FW);
        int we_ = (int)fminf(fmaxf(ceilf(tw1),  0.0f), (float)FW);
        hs = hs_; H = he_ - hs_; ws = ws_; Wd = we_ - ws_;
    }

    // ---- LDS writes (wait on globals), one barrier ----
    f4* l0 = (f4*)lds;
    f4* l1 = (f4*)(lds + PLANE);
    l0[tid] = a0;
    l0[tid + 1024] = a1;
    if (tail) l0[tid + 2048] = a2;
    l1[tid] = b0;
    l1[tid + 1024] = b1;
    if (tail) l1[tid + 2048] = b2;
    __syncthreads();

    // ---- compute: thread t<512 sums its ROI's <=4x4 window ----
    if (tid < R) {
        const float* p = lds + b * PLANE;
        int wl = (ws < FW - 4) ? ws : (FW - 4);   // clamped start, in-bounds
        int j0 = ws - wl;
        int j1 = j0 + Wd;
        const float* basep = p + hs * FW + wl;
        float s = 0.0f;
        #pragma unroll
        for (int hh = 0; hh < 4; ++hh) {
            int rrow = (hh < H) ? hh : (H - 1);   // clamp: stays on staged rows
            const float* rowp = basep + rrow * FW;
            #pragma unroll
            for (int k = 0; k < 4; ++k) {
                s += (hh < H && k >= j0 && k < j1) ? rowp[k] : 0.0f;
            }
        }
        int area = H * Wd;
        out[(size_t)tid * NCH + ch] = (area > 0) ? s / (float)area : 0.0f;
    }
}

extern "C" void kernel_launch(void* const* d_in, const int* in_sizes, int n_in,
                              void* d_out, int out_size, void* d_ws, size_t ws_size,
                              hipStream_t stream) {
    const float* feat = (const float*)d_in[0];
    const float* rois = (const float*)d_in[1];
    float* out = (float*)d_out;
    int R = in_sizes[1] / 5;  // 512
    psroi_full_kernel<<<NCH, 1024, 0, stream>>>(feat, rois, out, R);
}

// Round 16
// 21.681 us; speedup vs baseline: 1.3081x; 1.0579x over previous
//
#include <hip/hip_runtime.h>

// PSRoIPool: features (B=2, C=1029, H=100, W=100) f32, rois (R=512, 5) f32.
// Output: (R, D=21, P=7, P=7) f32;  out[r*1029 + ch], ch=(d*7+ph)*7+pw.
//
// Correctness-critical (round 7): window bounds must match XLA-CPU fast-math:
// bin = roi * float(1/7) (reciprocal multiply, NOT true divide), then
// fmaf(p, bin, s). Changing either re-breaks the knife-edge ROI (absmax 0.6).
//
// Perf (round 16): r15 (full-plane pair, 2 blocks/CU) streamed at only 3.6
// TB/s: with 2 blocks/CU, each block's drain->barrier->compute->retire gap
// leaves the CU's load pipe empty ~45% of the time. This round: block =
// (channel, batch) stages ONE 40 KB plane, grid (1029,2), 512 thr,
// 4 blocks/CU (160 KB LDS, 32 waves/CU) -> 3 neighbors stream while one
// computes. Same total traffic (each plane staged once, 82 MB). Thread t
// owns ROI t, computes iff roi.b == blockIdx.y (each output written once).

#define POOLED 7
#define GROUP 7
#define OUT_DIM 21
#define FH 100
#define FW 100
#define NCH (OUT_DIM * GROUP * GROUP)  // 1029
#define PLANE (FH * FW)                // 10000 floats
#define NF4 (PLANE / 4)                // 2500 f4 per plane

typedef float f4 __attribute__((ext_vector_type(4)));
typedef f4 __attribute__((aligned(16))) f4a;

__device__ __forceinline__ float fbar(float x) { asm volatile("" : "+v"(x)); return x; }

__global__ __launch_bounds__(512, 8) void psroi_split_kernel(
    const float* __restrict__ feat,
    const float* __restrict__ rois,
    float* __restrict__ out,
    int R)
{
    __shared__ float lds[PLANE];              // 40 KB: one (ch, b) plane
    const int ch  = blockIdx.x;               // 0..1028
    const int yb  = blockIdx.y;               // batch 0/1
    const int tid = threadIdx.x;              // 0..511

    // ---- issue all staging loads first (5 independent dwordx4) ----
    const f4a* src = (const f4a*)(feat + ((size_t)yb * NCH + ch) * PLANE);
    const bool tail = tid < (NF4 - 2048);     // 452 threads carry the remainder
    f4 a0 = src[tid];
    f4 a1 = src[tid + 512];
    f4 a2 = src[tid + 1024];
    f4 a3 = src[tid + 1536];
    f4 a4 = tail ? src[tid + 2048] : f4{0, 0, 0, 0};

    // ---- ROI bounds in the load-latency shadow (thread t owns ROI t) ----
    int H = 0, Wd = 0, hs = 0, ws = 0, b = -1;
    if (tid < R) {
        const float* roi = rois + (size_t)tid * 5;
        b = (int)roi[0];
        const float rcp7  = 1.0f / 7.0f;
        const float scale = 0.0625f;
        const int pw = ch % GROUP;
        const int ph = (ch / GROUP) % GROUP;
        const float phf = (float)ph;
        const float pwf = (float)pw;

        float sw = rintf(roi[1]) * scale;     // exact f32: k/16, k<25600
        float sh = rintf(roi[2]) * scale;
        float ew = (rintf(roi[3]) + 1.0f) * scale;
        float eh = (rintf(roi[4]) + 1.0f) * scale;
        float roi_w = fmaxf(ew - sw, 0.1f);
        float roi_h = fmaxf(eh - sh, 0.1f);

        // XLA-CPU fast-math semantics: reciprocal multiply + fused mul-add
        float bin_w = fbar(roi_w * rcp7);
        float bin_h = fbar(roi_h * rcp7);
        float th0 = __builtin_fmaf(phf,        bin_h, sh);
        float th1 = __builtin_fmaf(phf + 1.0f, bin_h, sh);
        float tw0 = __builtin_fmaf(pwf,        bin_w, sw);
        float tw1 = __builtin_fmaf(pwf + 1.0f, bin_w, sw);

        int hs_ = (int)fminf(fmaxf(floorf(th0), 0.0f), (float)FH);
        int he_ = (int)fminf(fmaxf(ceilf(th1),  0.0f), (float)FH);
        int ws_ = (int)fminf(fmaxf(floorf(tw0), 0.0f), (float)FW);
        int we_ = (int)fminf(fmaxf(ceilf(tw1),  0.0f), (float)FW);
        hs = hs_; H = he_ - hs_; ws = ws_; Wd = we_ - ws_;
    }

    // ---- LDS writes (wait on globals), one barrier ----
    f4* l = (f4*)lds;
    l[tid] = a0;
    l[tid + 512]  = a1;
    l[tid + 1024] = a2;
    l[tid + 1536] = a3;
    if (tail) l[tid + 2048] = a4;
    __syncthreads();

    // ---- compute: thread t sums its ROI's <=4x4 window iff batch matches ----
    if (tid < R && b == yb) {
        int wl = (ws < FW - 4) ? ws : (FW - 4);   // clamped start, in-bounds
        int j0 = ws - wl;
        int j1 = j0 + Wd;
        const float* basep = lds + hs * FW + wl;
        float s = 0.0f;
        #pragma unroll
        for (int hh = 0; hh < 4; ++hh) {
            int rrow = (hh < H) ? hh : (H - 1);   // clamp: stays on staged rows
            const float* rowp = basep + rrow * FW;
            #pragma unroll
            for (int k = 0; k < 4; ++k) {
                s += (hh < H && k >= j0 && k < j1) ? rowp[k] : 0.0f;
            }
        }
        int area = H * Wd;
        out[(size_t)tid * NCH + ch] = (area > 0) ? s / (float)area : 0.0f;
    }
}

extern "C" void kernel_launch(void* const* d_in, const int* in_sizes, int n_in,
                              void* d_out, int out_size, void* d_ws, size_t ws_size,
                              hipStream_t stream) {
    const float* feat = (const float*)d_in[0];
    const float* rois = (const float*)d_in[1];
    float* out = (float*)d_out;
    int R = in_sizes[1] / 5;  // 512
    dim3 grid(NCH, 2);
    psroi_split_kernel<<<grid, 512, 0, stream>>>(feat, rois, out, R);
}